// Round 7
// baseline (6662.117 us; speedup 1.0000x reference)
//
#include <hip/hip_runtime.h>
#include <hip/hip_bf16.h>
#include <hip/hip_fp16.h>

#define BT 16384
#define F 32
#define H 256
#define FH 8192
#define CHUNK 4096

typedef _Float16 half8 __attribute__((ext_vector_type(8)));
typedef float float4v __attribute__((ext_vector_type(4)));

#define GLD_LDS(gsrc, ldst) \
    __builtin_amdgcn_global_load_lds( \
        (const __attribute__((address_space(1))) void*)(gsrc), \
        (__attribute__((address_space(3))) void*)(ldst), 16, 0, 0)

#define MFMA16 __builtin_amdgcn_mfma_f32_16x16x32_f16

// ---------------------------------------------------------------------------
// Prep: transpose w2/wg/wf (F,K,N) fp32 -> [f][n][k] fp16
// ---------------------------------------------------------------------------
__global__ __launch_bounds__(256) void transpose_w_kernel(
    const float* __restrict__ w2, const float* __restrict__ wg,
    const float* __restrict__ wf, _Float16* __restrict__ wt)
{
    __shared__ float tile[64][65];
    int bid = blockIdx.x;
    int tens = bid >> 9, rem = bid & 511;
    int f = rem >> 4, tl = rem & 15;
    int hb = (tl >> 2) * 64, nb = (tl & 3) * 64;
    const float* src = (tens == 0 ? w2 : (tens == 1 ? wg : wf)) + f * 65536;
    _Float16* dst = wt + (size_t)tens * 2097152 + f * 65536;
    int lane = threadIdx.x & 63, w = threadIdx.x >> 6;
    for (int i = 0; i < 16; ++i) {
        int r = i * 4 + w;
        tile[r][lane] = src[(hb + r) * 256 + nb + lane];
    }
    __syncthreads();
    for (int i = 0; i < 16; ++i) {
        int c = i * 4 + w;
        dst[(nb + c) * 256 + hb + lane] = (_Float16)tile[lane][c];
    }
}

// ---------------------------------------------------------------------------
// Prep: wcat[n][k] fp16, n<256 from sw1 (8192,256), n in [256,288) from ssw
// ---------------------------------------------------------------------------
__global__ __launch_bounds__(256) void transpose_s_kernel(
    const float* __restrict__ sw1, const float* __restrict__ ssw,
    _Float16* __restrict__ wcat)
{
    __shared__ float tile[64][65];
    int bid = blockIdx.x;
    int lane = threadIdx.x & 63, w = threadIdx.x >> 6;
    int t = threadIdx.x;
    if (bid < 512) {
        int k0 = (bid >> 2) * 64, n0 = (bid & 3) * 64;
        for (int i = 0; i < 16; ++i) {
            int r = i * 4 + w;
            tile[r][lane] = sw1[(size_t)(k0 + r) * 256 + n0 + lane];
        }
        __syncthreads();
        for (int i = 0; i < 16; ++i) {
            int c = i * 4 + w;
            wcat[(size_t)(n0 + c) * FH + k0 + lane] = (_Float16)tile[lane][c];
        }
    } else {
        int k0 = (bid - 512) * 64;
        for (int i = 0; i < 8; ++i) {
            int idx = t + i * 256;
            int r = idx >> 5, cc = idx & 31;
            tile[r][cc] = ssw[(size_t)(k0 + r) * 32 + cc];
        }
        __syncthreads();
        for (int i = 0; i < 8; ++i) {
            int idx = t + i * 256;
            int c = idx >> 6, rr = idx & 63;
            wcat[(size_t)(256 + c) * FH + k0 + rr] = (_Float16)tile[rr][c];
        }
    }
}

// ---------------------------------------------------------------------------
// Stage B tiles (256x256 fp16 weights, [n][k]) through Bs (2048x8, xor
// swizzle) and MFMA against register-resident A-frags. 512 threads.
// ---------------------------------------------------------------------------
__device__ __forceinline__ void stageB_mfma(
    const _Float16* __restrict__ Bsrc, _Float16* Bs,
    const half8 a[2][8], float4v acc[2][4],
    int t, int ngrp, int ln, int q)
{
    for (int kc = 0; kc < 4; ++kc) {
        __syncthreads();
#pragma unroll
        for (int it = 0; it < 4; ++it) {
            int s = it * 512 + t;
            int n = s >> 3;
            int c = (s & 7) ^ (n & 7);
            GLD_LDS(Bsrc + n * 256 + kc * 64 + c * 8, Bs + s * 8);
        }
        __syncthreads();
#pragma unroll
        for (int ks = 0; ks < 2; ++ks) {
            int ku = kc * 2 + ks;
#pragma unroll
            for (int nt = 0; nt < 4; ++nt) {
                int n = ngrp * 64 + nt * 16 + ln;
                int cp = (ks * 4 + q) ^ (n & 7);
                half8 b8 = *(const half8*)&Bs[n * 64 + cp * 8];
                acc[0][nt] = MFMA16(a[0][ku], b8, acc[0][nt], 0, 0, 0);
                acc[1][nt] = MFMA16(a[1][ku], b8, acc[1][nt], 0, 0, 0);
            }
        }
    }
}

// ---------------------------------------------------------------------------
// GRN core, M=64, 512 threads, reg-A + As/Bs LDS union. Returns normalized
// y in yv (C-layout: m = mgrp*32+mt*16+q*4+r, n = ngrp*64+nt*16+ln).
// On exit As (region0) holds h2-garbage; caller may overwrite after barrier.
// ---------------------------------------------------------------------------
__device__ __forceinline__ void grn_f(
    int f, size_t tokg, const float* __restrict__ x,
    const float* __restrict__ w1, const float* __restrict__ b1,
    const float* __restrict__ b2, const float* __restrict__ bg,
    const float* __restrict__ bfv_, const float* __restrict__ gamma,
    const float* __restrict__ beta, const float* __restrict__ wsk,
    const float* __restrict__ bsk,
    const _Float16* __restrict__ w2t, const _Float16* __restrict__ wgt,
    const _Float16* __restrict__ wft,
    _Float16* As, _Float16* Bs, float* xs, float* red, float* mv,
    int t, int mgrp, int ngrp, int ln, int q, float4v yv[2][4])
{
    __syncthreads();                       // region0 + xs free
    if (t < 64) xs[t] = x[(tokg + t) * F + f];
    __syncthreads();
    // elu(x*w1+b1) -> As [m][k]
    {
        int h = t & 255, ig = t >> 8;
        float w1v = w1[f * H + h], b1v = b1[f * H + h];
#pragma unroll 4
        for (int i = ig * 32; i < ig * 32 + 32; ++i) {
            float z = xs[i] * w1v + b1v;
            As[i * 264 + h] = (_Float16)(z > 0.f ? z : (expf(z) - 1.f));
        }
    }
    __syncthreads();
    half8 a1[2][8];
#pragma unroll
    for (int mt = 0; mt < 2; ++mt)
#pragma unroll
        for (int ku = 0; ku < 8; ++ku)
            a1[mt][ku] = *(const half8*)&As[(mgrp * 32 + mt * 16 + ln) * 264 + ku * 32 + q * 8];
    float4v acc1[2][4];
#pragma unroll
    for (int mt = 0; mt < 2; ++mt)
#pragma unroll
        for (int nt = 0; nt < 4; ++nt)
#pragma unroll
            for (int r = 0; r < 4; ++r) acc1[mt][nt][r] = 0.f;
    stageB_mfma(w2t + (size_t)f * 65536, Bs, a1, acc1, t, ngrp, ln, q);
    __syncthreads();                       // stage1 done; region0 free
    // h2 + b2 -> As
    {
        const float* b2f = b2 + f * H;
#pragma unroll
        for (int mt = 0; mt < 2; ++mt)
#pragma unroll
            for (int nt = 0; nt < 4; ++nt) {
                int n = ngrp * 64 + nt * 16 + ln;
                float b2v = b2f[n];
#pragma unroll
                for (int r = 0; r < 4; ++r) {
                    int m = mgrp * 32 + mt * 16 + q * 4 + r;
                    As[m * 264 + n] = (_Float16)(acc1[mt][nt][r] + b2v);
                }
            }
    }
    __syncthreads();
    half8 a2[2][8];
#pragma unroll
    for (int mt = 0; mt < 2; ++mt)
#pragma unroll
        for (int ku = 0; ku < 8; ++ku)
            a2[mt][ku] = *(const half8*)&As[(mgrp * 32 + mt * 16 + ln) * 264 + ku * 32 + q * 8];
    float4v aG[2][4], aF[2][4];
#pragma unroll
    for (int mt = 0; mt < 2; ++mt)
#pragma unroll
        for (int nt = 0; nt < 4; ++nt)
#pragma unroll
            for (int r = 0; r < 4; ++r) { aG[mt][nt][r] = 0.f; aF[mt][nt][r] = 0.f; }
    stageB_mfma(wgt + (size_t)f * 65536, Bs, a2, aG, t, ngrp, ln, q);
    stageB_mfma(wft + (size_t)f * 65536, Bs, a2, aF, t, ngrp, ln, q);
    // GLU + residual (regs)
    {
        const float* bgf = bg + f * H;
        const float* bff = bfv_ + f * H;
        const float* wsf = wsk + f * H;
        const float* bsf = bsk + f * H;
#pragma unroll
        for (int mt = 0; mt < 2; ++mt)
#pragma unroll
            for (int nt = 0; nt < 4; ++nt) {
                int n = ngrp * 64 + nt * 16 + ln;
                float bgv = bgf[n], bfv = bff[n], wsv = wsf[n], bsv = bsf[n];
#pragma unroll
                for (int r = 0; r < 4; ++r) {
                    int m = mgrp * 32 + mt * 16 + q * 4 + r;
                    float cg = aG[mt][nt][r] + bgv;
                    float cf = aF[mt][nt][r] + bfv;
                    float sig = 1.f / (1.f + expf(-cg));
                    yv[mt][nt][r] = sig * cf + xs[m] * wsv + bsv;
                }
            }
    }
    // LayerNorm: 16-lane butterfly partials -> red
#pragma unroll
    for (int mt = 0; mt < 2; ++mt)
#pragma unroll
        for (int r = 0; r < 4; ++r) {
            float s1 = 0.f, s2 = 0.f;
#pragma unroll
            for (int nt = 0; nt < 4; ++nt) {
                float v = yv[mt][nt][r];
                s1 += v; s2 += v * v;
            }
#pragma unroll
            for (int off = 1; off < 16; off <<= 1) {
                s1 += __shfl_xor(s1, off, 16);
                s2 += __shfl_xor(s2, off, 16);
            }
            if (ln == 0) {
                int m = mgrp * 32 + mt * 16 + q * 4 + r;
                red[m * 4 + ngrp] = s1;
                red[256 + m * 4 + ngrp] = s2;
            }
        }
    __syncthreads();                       // all MFMA + red done
    if (t < 64) {
        float a = red[t * 4] + red[t * 4 + 1] + red[t * 4 + 2] + red[t * 4 + 3];
        float b = red[256 + t * 4] + red[256 + t * 4 + 1] + red[256 + t * 4 + 2] + red[256 + t * 4 + 3];
        float mean = a * (1.f / 256.f);
        float var = b * (1.f / 256.f) - mean * mean;
        mv[t] = mean;
        mv[64 + t] = rsqrtf(var + 1e-5f);
    }
    __syncthreads();
    {
        const float* gf = gamma + f * H;
        const float* bf2 = beta + f * H;
#pragma unroll
        for (int mt = 0; mt < 2; ++mt)
#pragma unroll
            for (int nt = 0; nt < 4; ++nt) {
                int n = ngrp * 64 + nt * 16 + ln;
                float gv = gf[n], bv = bf2[n];
#pragma unroll
                for (int r = 0; r < 4; ++r) {
                    int m = mgrp * 32 + mt * 16 + q * 4 + r;
                    yv[mt][nt][r] = (yv[mt][nt][r] - mv[m]) * mv[64 + m] * gv + bv;
                }
            }
    }
}

// ---------------------------------------------------------------------------
// PASS 1: grid (CHUNK/64, 16). Block = 64 tokens x 2 features.
// For each f: grn_f -> y -> As -> a3 regs -> sel partial vs wcat_f (K=256).
// Epilogue: fp32 atomics into acc[CHUNK][288] (zero-inited; bias in tail).
// ---------------------------------------------------------------------------
__global__ __launch_bounds__(512, 8) void pass1_kernel(
    const float* __restrict__ x, const float* __restrict__ w1, const float* __restrict__ b1,
    const float* __restrict__ b2, const float* __restrict__ bg, const float* __restrict__ bfv_,
    const float* __restrict__ gamma, const float* __restrict__ beta,
    const float* __restrict__ wsk, const float* __restrict__ bsk,
    const _Float16* __restrict__ w2t, const _Float16* __restrict__ wgt,
    const _Float16* __restrict__ wft, const _Float16* __restrict__ wcat,
    float* __restrict__ acc, int tok_base)
{
    __shared__ __align__(16) char smem[39680];
    _Float16* As = (_Float16*)smem;            // 64x264 fp16 (union w/ Bs)
    _Float16* Bs = (_Float16*)smem;            // up to 2304x8 fp16 (36864 B)
    float* xs  = (float*)(smem + 36864);       // 64
    float* red = (float*)(smem + 37120);       // 512
    float* mv  = (float*)(smem + 39168);       // 128

    const int t = threadIdx.x;
    const int w = t >> 6;
    const int mgrp = w >> 2, ngrp = w & 3;
    const int ln = t & 15, q = (t & 63) >> 4;
    const int NT = (ngrp < 2) ? 5 : 4;
    const int tok0 = blockIdx.x * 64;          // chunk-local
    const size_t tokg = (size_t)(tok_base + tok0);

    float4v selacc[2][5];
#pragma unroll
    for (int mt = 0; mt < 2; ++mt)
#pragma unroll
        for (int i = 0; i < 5; ++i)
#pragma unroll
            for (int r = 0; r < 4; ++r) selacc[mt][i][r] = 0.f;

    float4v yv[2][4];
    for (int fi = 0; fi < 2; ++fi) {
        int f = blockIdx.y * 2 + fi;
        grn_f(f, tokg, x, w1, b1, b2, bg, bfv_, gamma, beta, wsk, bsk,
              w2t, wgt, wft, As, Bs, xs, red, mv, t, mgrp, ngrp, ln, q, yv);
        // y -> As (A-layout fp16)
#pragma unroll
        for (int mt = 0; mt < 2; ++mt)
#pragma unroll
            for (int nt = 0; nt < 4; ++nt) {
                int n = ngrp * 64 + nt * 16 + ln;
#pragma unroll
                for (int r = 0; r < 4; ++r) {
                    int m = mgrp * 32 + mt * 16 + q * 4 + r;
                    As[m * 264 + n] = (_Float16)yv[mt][nt][r];
                }
            }
        __syncthreads();
        half8 a3[2][8];
#pragma unroll
        for (int mt = 0; mt < 2; ++mt)
#pragma unroll
            for (int ku = 0; ku < 8; ++ku)
                a3[mt][ku] = *(const half8*)&As[(mgrp * 32 + mt * 16 + ln) * 264 + ku * 32 + q * 8];
        // sel partial: y_f (64x256) @ wcat_f^T (256x288)
        for (int kc = 0; kc < 4; ++kc) {
            __syncthreads();
#pragma unroll
            for (int it = 0; it < 5; ++it) {
                int s = it * 512 + t;
                if (s < 2304) {
                    int nb = s >> 3;
                    int cb = (s & 7) ^ (nb & 7);
                    GLD_LDS(wcat + (size_t)nb * FH + f * 256 + kc * 64 + cb * 8, Bs + s * 8);
                }
            }
            __syncthreads();
#pragma unroll
            for (int ks = 0; ks < 2; ++ks) {
                int ku = kc * 2 + ks;
                for (int i = 0; i < NT; ++i) {
                    int row = (ngrp + 4 * i) * 16 + ln;
                    int cp = (ks * 4 + q) ^ (row & 7);
                    half8 b8 = *(const half8*)&Bs[row * 64 + cp * 8];
#pragma unroll
                    for (int mt = 0; mt < 2; ++mt)
                        selacc[mt][i] = MFMA16(a3[mt][ku], b8, selacc[mt][i], 0, 0, 0);
                }
            }
        }
    }
    // epilogue: atomics into acc (chunk-local)
    for (int i = 0; i < NT; ++i) {
        int n = (ngrp + 4 * i) * 16 + ln;
#pragma unroll
        for (int mt = 0; mt < 2; ++mt)
#pragma unroll
            for (int r = 0; r < 4; ++r) {
                int m = mgrp * 32 + mt * 16 + q * 4 + r;
                unsafeAtomicAdd(&acc[(size_t)(tok0 + m) * 288 + n], selacc[mt][i][r]);
            }
    }
}

// ---------------------------------------------------------------------------
// TAIL: acc+bias -> elu -> fc2 -> GLU -> LN -> softmax -> wbuf. 8 tok/block.
// ---------------------------------------------------------------------------
__global__ __launch_bounds__(256) void tail_kernel(
    const float* __restrict__ acc,
    const float* __restrict__ sb1, const float* __restrict__ ssb,
    const float* __restrict__ sw2, const float* __restrict__ sb2,
    const float* __restrict__ swg, const float* __restrict__ sbg,
    const float* __restrict__ swf, const float* __restrict__ sbf,
    const float* __restrict__ sgam, const float* __restrict__ sbet,
    float* __restrict__ wbuf, int tok_base)
{
    __shared__ float sw2s[256 * 32];
    __shared__ float swgs[1024], swfs[1024];
    __shared__ float shv[8][257];
    const int t = threadIdx.x;
    for (int i = 0; i < 32; ++i) sw2s[t + i * 256] = sw2[t + i * 256];
    for (int i = 0; i < 4; ++i) {
        swgs[t + i * 256] = swg[t + i * 256];
        swfs[t + i * 256] = swf[t + i * 256];
    }
    for (int i = 0; i < 8; ++i) {
        int idx = t + i * 256;
        int gg = idx >> 8, col = idx & 255;
        float z = acc[(size_t)(blockIdx.x * 8 + gg) * 288 + col] + sb1[col];
        shv[gg][col] = z > 0.f ? z : (expf(z) - 1.f);
    }
    __syncthreads();
    const int g = t >> 5;
    const int j = t & 31;
    const int token = blockIdx.x * 8 + g;              // chunk-local
    float p = sb2[j];
    for (int k = 0; k < 256; ++k) p += shv[g][k] * sw2s[k * 32 + j];
    float gacc = sbg[j], uacc = sbf[j];
#pragma unroll 8
    for (int i = 0; i < 32; ++i) {
        float tv = __shfl(p, i, 32);
        gacc += tv * swgs[i * 32 + j];
        uacc += tv * swfs[i * 32 + j];
    }
    float sig = 1.f / (1.f + expf(-gacc));
    float sv = acc[(size_t)token * 288 + 256 + j] + ssb[j] + sig * uacc;
    float s1 = sv, s2 = sv * sv;
    for (int off = 16; off; off >>= 1) {
        s1 += __shfl_xor(s1, off, 32);
        s2 += __shfl_xor(s2, off, 32);
    }
    float mean = s1 * (1.f / 32.f);
    float var = s2 * (1.f / 32.f) - mean * mean;
    float v = (sv - mean) * rsqrtf(var + 1e-5f) * sgam[j] + sbet[j];
    float mx = v;
    for (int off = 16; off; off >>= 1) mx = fmaxf(mx, __shfl_xor(mx, off, 32));
    float e = expf(v - mx);
    float ssum = e;
    for (int off = 16; off; off >>= 1) ssum += __shfl_xor(ssum, off, 32);
    wbuf[(size_t)(tok_base + token) * 32 + j] = e / ssum;
}

// ---------------------------------------------------------------------------
// PASS 2: grid (BT/64, 4). Block = 64 tokens x 8 features. Recompute y_f,
// accumulate w_f*y_f in regs, atomic-add into zeroed out (4 adds/elem).
// ---------------------------------------------------------------------------
__global__ __launch_bounds__(512, 8) void pass2_kernel(
    const float* __restrict__ x, const float* __restrict__ w1, const float* __restrict__ b1,
    const float* __restrict__ b2, const float* __restrict__ bg, const float* __restrict__ bfv_,
    const float* __restrict__ gamma, const float* __restrict__ beta,
    const float* __restrict__ wsk, const float* __restrict__ bsk,
    const _Float16* __restrict__ w2t, const _Float16* __restrict__ wgt,
    const _Float16* __restrict__ wft, const float* __restrict__ wbuf,
    float* __restrict__ out)
{
    __shared__ __align__(16) char smem[38656];
    _Float16* As = (_Float16*)smem;            // union w/ Bs (33792 B)
    _Float16* Bs = (_Float16*)smem;
    float* xs  = (float*)(smem + 33792);       // 64
    float* red = (float*)(smem + 34048);       // 512
    float* mv  = (float*)(smem + 36096);       // 128
    float* wls = (float*)(smem + 36608);       // 64 x 8

    const int t = threadIdx.x;
    const int w = t >> 6;
    const int mgrp = w >> 2, ngrp = w & 3;
    const int ln = t & 15, q = (t & 63) >> 4;
    const size_t tokg = (size_t)blockIdx.x * 64;
    const int f0 = blockIdx.y * 8;

    {
        int m = t >> 3, fi = t & 7;
        wls[t] = wbuf[(tokg + m) * 32 + f0 + fi];
    }

    float4v oacc[2][4];
#pragma unroll
    for (int mt = 0; mt < 2; ++mt)
#pragma unroll
        for (int nt = 0; nt < 4; ++nt)
#pragma unroll
            for (int r = 0; r < 4; ++r) oacc[mt][nt][r] = 0.f;

    float4v yv[2][4];
    for (int fi = 0; fi < 8; ++fi) {
        int f = f0 + fi;
        grn_f(f, tokg, x, w1, b1, b2, bg, bfv_, gamma, beta, wsk, bsk,
              w2t, wgt, wft, As, Bs, xs, red, mv, t, mgrp, ngrp, ln, q, yv);
#pragma unroll
        for (int mt = 0; mt < 2; ++mt)
#pragma unroll
            for (int r = 0; r < 4; ++r) {
                int m = mgrp * 32 + mt * 16 + q * 4 + r;
                float wfv = wls[m * 8 + fi];
#pragma unroll
                for (int nt = 0; nt < 4; ++nt)
                    oacc[mt][nt][r] += wfv * yv[mt][nt][r];
            }
    }
#pragma unroll
    for (int mt = 0; mt < 2; ++mt)
#pragma unroll
        for (int nt = 0; nt < 4; ++nt) {
            int n = ngrp * 64 + nt * 16 + ln;
#pragma unroll
            for (int r = 0; r < 4; ++r) {
                int m = mgrp * 32 + mt * 16 + q * 4 + r;
                unsafeAtomicAdd(&out[(tokg + m) * H + n], oacc[mt][nt][r]);
            }
        }
}

// ---------------------------------------------------------------------------
extern "C" void kernel_launch(void* const* d_in, const int* in_sizes, int n_in,
                              void* d_out, int out_size, void* d_ws, size_t ws_size,
                              hipStream_t stream)
{
    (void)in_sizes; (void)n_in; (void)out_size; (void)ws_size;
    const float* x    = (const float*)d_in[0];
    const float* w1   = (const float*)d_in[1];
    const float* b1   = (const float*)d_in[2];
    const float* w2   = (const float*)d_in[3];
    const float* b2   = (const float*)d_in[4];
    const float* wg   = (const float*)d_in[5];
    const float* bg   = (const float*)d_in[6];
    const float* wf   = (const float*)d_in[7];
    const float* bfp  = (const float*)d_in[8];
    const float* gamma= (const float*)d_in[9];
    const float* beta = (const float*)d_in[10];
    const float* wsk  = (const float*)d_in[11];
    const float* bsk  = (const float*)d_in[12];
    const float* sw1  = (const float*)d_in[13];
    const float* sb1  = (const float*)d_in[14];
    const float* sw2  = (const float*)d_in[15];
    const float* sb2  = (const float*)d_in[16];
    const float* swg  = (const float*)d_in[17];
    const float* sbg  = (const float*)d_in[18];
    const float* swf  = (const float*)d_in[19];
    const float* sbf  = (const float*)d_in[20];
    const float* sgam = (const float*)d_in[21];
    const float* sbet = (const float*)d_in[22];
    const float* ssw  = (const float*)d_in[23];
    const float* ssb  = (const float*)d_in[24];

    char* ws = (char*)d_ws;
    _Float16* wt   = (_Float16*)ws;                     // 12.58 MB
    _Float16* wcat = (_Float16*)(ws + 12582912);        // 4.72 MB
    float* acc     = (float*)(ws + 17301504);           // 4096x288 f32 = 4.72 MB
    float* wbuf    = (float*)(ws + 22020096);           // 16384x32 f32 = 2 MB
    float* out     = (float*)d_out;
    // total ws: 24.1 MB (ws_size known >= 26.3 MB)

    hipLaunchKernelGGL(transpose_w_kernel, dim3(1536), dim3(256), 0, stream, w2, wg, wf, wt);
    hipLaunchKernelGGL(transpose_s_kernel, dim3(640), dim3(256), 0, stream, sw1, ssw, wcat);
    hipMemsetAsync(out, 0, (size_t)BT * H * sizeof(float), stream);
    for (int c = 0; c < BT / CHUNK; ++c) {
        int tb = c * CHUNK;
        hipMemsetAsync(acc, 0, (size_t)CHUNK * 288 * sizeof(float), stream);
        hipLaunchKernelGGL(pass1_kernel, dim3(CHUNK / 64, 16), dim3(512), 0, stream,
                           x, w1, b1, b2, bg, bfp, gamma, beta, wsk, bsk,
                           wt, wt + 2097152, wt + 2 * 2097152, wcat, acc, tb);
        hipLaunchKernelGGL(tail_kernel, dim3(CHUNK / 8), dim3(256), 0, stream,
                           acc, sb1, ssb, sw2, sb2, swg, sbg, swf, sbf,
                           sgam, sbet, wbuf, tb);
    }
    hipLaunchKernelGGL(pass2_kernel, dim3(BT / 64, 4), dim3(512), 0, stream,
                       x, w1, b1, b2, bg, bfp, gamma, beta, wsk, bsk,
                       wt, wt + 2097152, wt + 2 * 2097152, wbuf, out);
}

// Round 8
// 2117.100 us; speedup vs baseline: 3.1468x; 3.1468x over previous
//
#include <hip/hip_runtime.h>
#include <hip/hip_bf16.h>
#include <hip/hip_fp16.h>

#define BT 16384
#define F 32
#define H 256
#define FH 8192
#define CHUNK 4096

typedef _Float16 half8 __attribute__((ext_vector_type(8)));
typedef float float4v __attribute__((ext_vector_type(4)));

#define GLD_LDS(gsrc, ldst) \
    __builtin_amdgcn_global_load_lds( \
        (const __attribute__((address_space(1))) void*)(gsrc), \
        (__attribute__((address_space(3))) void*)(ldst), 16, 0, 0)

#define MFMA16 __builtin_amdgcn_mfma_f32_16x16x32_f16

// ---------------------------------------------------------------------------
// Prep: transpose w2/wg/wf (F,K,N) fp32 -> [f][n][k] fp16
// ---------------------------------------------------------------------------
__global__ __launch_bounds__(256) void transpose_w_kernel(
    const float* __restrict__ w2, const float* __restrict__ wg,
    const float* __restrict__ wf, _Float16* __restrict__ wt)
{
    __shared__ float tile[64][65];
    int bid = blockIdx.x;
    int tens = bid >> 9, rem = bid & 511;
    int f = rem >> 4, tl = rem & 15;
    int hb = (tl >> 2) * 64, nb = (tl & 3) * 64;
    const float* src = (tens == 0 ? w2 : (tens == 1 ? wg : wf)) + f * 65536;
    _Float16* dst = wt + (size_t)tens * 2097152 + f * 65536;
    int lane = threadIdx.x & 63, w = threadIdx.x >> 6;
    for (int i = 0; i < 16; ++i) {
        int r = i * 4 + w;
        tile[r][lane] = src[(hb + r) * 256 + nb + lane];
    }
    __syncthreads();
    for (int i = 0; i < 16; ++i) {
        int c = i * 4 + w;
        dst[(nb + c) * 256 + hb + lane] = (_Float16)tile[lane][c];
    }
}

// ---------------------------------------------------------------------------
// Prep: wcat[n][k] fp16, n<256 from sw1 (8192,256), n in [256,288) from ssw
// ---------------------------------------------------------------------------
__global__ __launch_bounds__(256) void transpose_s_kernel(
    const float* __restrict__ sw1, const float* __restrict__ ssw,
    _Float16* __restrict__ wcat)
{
    __shared__ float tile[64][65];
    int bid = blockIdx.x;
    int lane = threadIdx.x & 63, w = threadIdx.x >> 6;
    int t = threadIdx.x;
    if (bid < 512) {
        int k0 = (bid >> 2) * 64, n0 = (bid & 3) * 64;
        for (int i = 0; i < 16; ++i) {
            int r = i * 4 + w;
            tile[r][lane] = sw1[(size_t)(k0 + r) * 256 + n0 + lane];
        }
        __syncthreads();
        for (int i = 0; i < 16; ++i) {
            int c = i * 4 + w;
            wcat[(size_t)(n0 + c) * FH + k0 + lane] = (_Float16)tile[lane][c];
        }
    } else {
        int k0 = (bid - 512) * 64;
        for (int i = 0; i < 8; ++i) {
            int idx = t + i * 256;
            int r = idx >> 5, cc = idx & 31;
            tile[r][cc] = ssw[(size_t)(k0 + r) * 32 + cc];
        }
        __syncthreads();
        for (int i = 0; i < 8; ++i) {
            int idx = t + i * 256;
            int c = idx >> 6, rr = idx & 63;
            wcat[(size_t)(256 + c) * FH + k0 + rr] = (_Float16)tile[rr][c];
        }
    }
}

// ---------------------------------------------------------------------------
// Stage one 256x256 fp16 weight matrix ([n][k]) through Bs and MFMA against
// register-resident A-frags (one 16-row m-tile per wave). Fully unrolled:
// no dynamic register indexing. 512 threads.
// ---------------------------------------------------------------------------
__device__ __forceinline__ void stageB32(
    const _Float16* __restrict__ Bsrc, _Float16* Bs,
    const half8 a[8], float4v acc[4],
    int t, int ngrp, int ln, int q)
{
#pragma unroll
    for (int kc = 0; kc < 4; ++kc) {
        __syncthreads();
#pragma unroll
        for (int it = 0; it < 4; ++it) {
            int s = it * 512 + t;
            int n = s >> 3;
            int c = (s & 7) ^ (n & 7);
            GLD_LDS(Bsrc + n * 256 + kc * 64 + c * 8, Bs + s * 8);
        }
        __syncthreads();
#pragma unroll
        for (int ks = 0; ks < 2; ++ks) {
#pragma unroll
            for (int nt = 0; nt < 4; ++nt) {
                int n = ngrp * 64 + nt * 16 + ln;
                int cp = (ks * 4 + q) ^ (n & 7);
                half8 b8 = *(const half8*)&Bs[n * 64 + cp * 8];
                acc[nt] = MFMA16(a[kc * 2 + ks], b8, acc[nt], 0, 0, 0);
            }
        }
    }
}

// ---------------------------------------------------------------------------
// GRN core, M=32, 512 threads. Returns normalized y in yv:
// m = mgrp*16 + q*4 + r, n = ngrp*64 + nt*16 + ln.
// ---------------------------------------------------------------------------
__device__ __forceinline__ void grn32(
    int f, size_t tokg, const float* __restrict__ x,
    const float* __restrict__ w1, const float* __restrict__ b1,
    const float* __restrict__ b2, const float* __restrict__ bg,
    const float* __restrict__ bfv_, const float* __restrict__ gamma,
    const float* __restrict__ beta, const float* __restrict__ wsk,
    const float* __restrict__ bsk,
    const _Float16* __restrict__ w2t, const _Float16* __restrict__ wgt,
    const _Float16* __restrict__ wft,
    _Float16* As, _Float16* Bs, float* xs, float* red, float* mv,
    int t, int mgrp, int ngrp, int ln, int q, float4v yv[4])
{
    __syncthreads();                      // As/Bs/xs free from prior f
    if (t < 32) xs[t] = x[(tokg + t) * F + f];
    __syncthreads();
    // elu(x*w1+b1) -> As [32 rows x 256, stride 264]
    {
        int h = t & 255, hv = t >> 8;
        float w1v = w1[f * H + h], b1v = b1[f * H + h];
#pragma unroll
        for (int i = 0; i < 16; ++i) {
            int row = hv * 16 + i;
            float z = xs[row] * w1v + b1v;
            As[row * 264 + h] = (_Float16)(z > 0.f ? z : (expf(z) - 1.f));
        }
    }
    __syncthreads();
    half8 a1[8];
#pragma unroll
    for (int ku = 0; ku < 8; ++ku)
        a1[ku] = *(const half8*)&As[(mgrp * 16 + ln) * 264 + ku * 32 + q * 8];
    float4v c1[4];
#pragma unroll
    for (int nt = 0; nt < 4; ++nt)
#pragma unroll
        for (int r = 0; r < 4; ++r) c1[nt][r] = 0.f;
    stageB32(w2t + (size_t)f * 65536, Bs, a1, c1, t, ngrp, ln, q);
    __syncthreads();
    // h2 + b2 -> As
    {
        const float* b2f = b2 + f * H;
#pragma unroll
        for (int nt = 0; nt < 4; ++nt) {
            int n = ngrp * 64 + nt * 16 + ln;
            float b2v = b2f[n];
#pragma unroll
            for (int r = 0; r < 4; ++r) {
                int m = mgrp * 16 + q * 4 + r;
                As[m * 264 + n] = (_Float16)(c1[nt][r] + b2v);
            }
        }
    }
    __syncthreads();
    half8 a2[8];
#pragma unroll
    for (int ku = 0; ku < 8; ++ku)
        a2[ku] = *(const half8*)&As[(mgrp * 16 + ln) * 264 + ku * 32 + q * 8];
    float4v cG[4], cF[4];
#pragma unroll
    for (int nt = 0; nt < 4; ++nt)
#pragma unroll
        for (int r = 0; r < 4; ++r) { cG[nt][r] = 0.f; cF[nt][r] = 0.f; }
    stageB32(wgt + (size_t)f * 65536, Bs, a2, cG, t, ngrp, ln, q);
    stageB32(wft + (size_t)f * 65536, Bs, a2, cF, t, ngrp, ln, q);
    // GLU + residual
    {
        const float* bgf = bg + f * H;
        const float* bff = bfv_ + f * H;
        const float* wsf = wsk + f * H;
        const float* bsf = bsk + f * H;
#pragma unroll
        for (int nt = 0; nt < 4; ++nt) {
            int n = ngrp * 64 + nt * 16 + ln;
            float bgv = bgf[n], bfv = bff[n], wsv = wsf[n], bsv = bsf[n];
#pragma unroll
            for (int r = 0; r < 4; ++r) {
                int m = mgrp * 16 + q * 4 + r;
                float cg = cG[nt][r] + bgv;
                float cf = cF[nt][r] + bfv;
                float sig = 1.f / (1.f + expf(-cg));
                yv[nt][r] = sig * cf + xs[m] * wsv + bsv;
            }
        }
    }
    // LayerNorm partials: 16-lane butterfly -> red
#pragma unroll
    for (int r = 0; r < 4; ++r) {
        float s1 = 0.f, s2 = 0.f;
#pragma unroll
        for (int nt = 0; nt < 4; ++nt) {
            float v = yv[nt][r];
            s1 += v; s2 += v * v;
        }
#pragma unroll
        for (int off = 1; off < 16; off <<= 1) {
            s1 += __shfl_xor(s1, off, 16);
            s2 += __shfl_xor(s2, off, 16);
        }
        if (ln == 0) {
            int m = mgrp * 16 + q * 4 + r;
            red[m * 4 + ngrp] = s1;
            red[128 + m * 4 + ngrp] = s2;
        }
    }
    __syncthreads();
    if (t < 32) {
        float a = red[t * 4] + red[t * 4 + 1] + red[t * 4 + 2] + red[t * 4 + 3];
        float b = red[128 + t * 4] + red[128 + t * 4 + 1] + red[128 + t * 4 + 2] + red[128 + t * 4 + 3];
        float mean = a * (1.f / 256.f);
        float var = b * (1.f / 256.f) - mean * mean;
        mv[t] = mean;
        mv[32 + t] = rsqrtf(var + 1e-5f);
    }
    __syncthreads();
    {
        const float* gf = gamma + f * H;
        const float* bf2 = beta + f * H;
#pragma unroll
        for (int nt = 0; nt < 4; ++nt) {
            int n = ngrp * 64 + nt * 16 + ln;
            float gv = gf[n], bv = bf2[n];
#pragma unroll
            for (int r = 0; r < 4; ++r) {
                int m = mgrp * 16 + q * 4 + r;
                yv[nt][r] = (yv[nt][r] - mv[m]) * mv[32 + m] * gv + bv;
            }
        }
    }
}

// ---------------------------------------------------------------------------
// PASS 1: grid (CHUNK/32, 4). Block = 32 tokens x 8 features.
// Per f: grn32 -> y -> As -> a3 regs -> sel partial vs wcat_f (K=256),
// accumulated in selacc over 8 f. Epilogue: fp32 atomics into zeroed acc.
// ---------------------------------------------------------------------------
__global__ __launch_bounds__(512, 4) void pass1_kernel(
    const float* __restrict__ x, const float* __restrict__ w1, const float* __restrict__ b1,
    const float* __restrict__ b2, const float* __restrict__ bg, const float* __restrict__ bfv_,
    const float* __restrict__ gamma, const float* __restrict__ beta,
    const float* __restrict__ wsk, const float* __restrict__ bsk,
    const _Float16* __restrict__ w2t, const _Float16* __restrict__ wgt,
    const _Float16* __restrict__ wft, const _Float16* __restrict__ wcat,
    float* __restrict__ acc, int tok_base)
{
    __shared__ __align__(16) char smem[55168];
    _Float16* As = (_Float16*)smem;             // 32x264 fp16 [0,16896)
    _Float16* Bs = (_Float16*)(smem + 16896);   // 2304x8 fp16 [16896,53760)
    float* xs  = (float*)(smem + 53760);        // 32
    float* red = (float*)(smem + 53888);        // 256
    float* mv  = (float*)(smem + 54912);        // 64

    const int t = threadIdx.x;
    const int w = t >> 6;
    const int mgrp = w >> 2, ngrp = w & 3;
    const int ln = t & 15, q = (t & 63) >> 4;
    const int tok0 = blockIdx.x * 32;           // chunk-local
    const size_t tokg = (size_t)(tok_base + tok0);
    const int fg = blockIdx.y;

    float4v selacc[5];
#pragma unroll
    for (int i = 0; i < 5; ++i)
#pragma unroll
        for (int r = 0; r < 4; ++r) selacc[i][r] = 0.f;

    float4v yv[4];
    for (int fi = 0; fi < 8; ++fi) {
        int f = fg * 8 + fi;
        grn32(f, tokg, x, w1, b1, b2, bg, bfv_, gamma, beta, wsk, bsk,
              w2t, wgt, wft, As, Bs, xs, red, mv, t, mgrp, ngrp, ln, q, yv);
        // y -> As (A-layout fp16)
#pragma unroll
        for (int nt = 0; nt < 4; ++nt) {
            int n = ngrp * 64 + nt * 16 + ln;
#pragma unroll
            for (int r = 0; r < 4; ++r) {
                int m = mgrp * 16 + q * 4 + r;
                As[m * 264 + n] = (_Float16)yv[nt][r];
            }
        }
        __syncthreads();
        half8 a3[8];
#pragma unroll
        for (int ku = 0; ku < 8; ++ku)
            a3[ku] = *(const half8*)&As[(mgrp * 16 + ln) * 264 + ku * 32 + q * 8];
        // sel partial: y_f (32x256) @ wcat_f^T (256x288)
#pragma unroll
        for (int kc = 0; kc < 4; ++kc) {
            __syncthreads();
#pragma unroll
            for (int it = 0; it < 5; ++it) {
                int s = it * 512 + t;
                if (s < 2304) {
                    int nb = s >> 3;
                    int cb = (s & 7) ^ (nb & 7);
                    GLD_LDS(wcat + (size_t)nb * FH + f * 256 + kc * 64 + cb * 8, Bs + s * 8);
                }
            }
            __syncthreads();
#pragma unroll
            for (int ks = 0; ks < 2; ++ks) {
#pragma unroll
                for (int i = 0; i < 5; ++i) {
                    int ntg = ngrp + 4 * i;
                    if (ntg < 18) {
                        int row = ntg * 16 + ln;
                        int cp = (ks * 4 + q) ^ (row & 7);
                        half8 b8 = *(const half8*)&Bs[row * 64 + cp * 8];
                        selacc[i] = MFMA16(a3[kc * 2 + ks], b8, selacc[i], 0, 0, 0);
                    }
                }
            }
        }
    }
    // epilogue: atomics into acc (chunk-local, zero-inited)
#pragma unroll
    for (int i = 0; i < 5; ++i) {
        int ntg = ngrp + 4 * i;
        if (ntg < 18) {
            int n = ntg * 16 + ln;
#pragma unroll
            for (int r = 0; r < 4; ++r) {
                int m = tok0 + mgrp * 16 + q * 4 + r;
                unsafeAtomicAdd(&acc[(size_t)m * 288 + n], selacc[i][r]);
            }
        }
    }
}

// ---------------------------------------------------------------------------
// TAIL: acc+bias -> elu -> fc2 -> GLU -> LN -> softmax -> wbuf. 8 tok/block.
// ---------------------------------------------------------------------------
__global__ __launch_bounds__(256) void tail_kernel(
    const float* __restrict__ acc,
    const float* __restrict__ sb1, const float* __restrict__ ssb,
    const float* __restrict__ sw2, const float* __restrict__ sb2,
    const float* __restrict__ swg, const float* __restrict__ sbg,
    const float* __restrict__ swf, const float* __restrict__ sbf,
    const float* __restrict__ sgam, const float* __restrict__ sbet,
    float* __restrict__ wbuf, int tok_base)
{
    __shared__ float sw2s[256 * 32];
    __shared__ float swgs[1024], swfs[1024];
    __shared__ float shv[8][257];
    const int t = threadIdx.x;
    for (int i = 0; i < 32; ++i) sw2s[t + i * 256] = sw2[t + i * 256];
    for (int i = 0; i < 4; ++i) {
        swgs[t + i * 256] = swg[t + i * 256];
        swfs[t + i * 256] = swf[t + i * 256];
    }
    for (int i = 0; i < 8; ++i) {
        int idx = t + i * 256;
        int gg = idx >> 8, col = idx & 255;
        float z = acc[(size_t)(blockIdx.x * 8 + gg) * 288 + col] + sb1[col];
        shv[gg][col] = z > 0.f ? z : (expf(z) - 1.f);
    }
    __syncthreads();
    const int g = t >> 5;
    const int j = t & 31;
    const int token = blockIdx.x * 8 + g;               // chunk-local
    float p = sb2[j];
    for (int k = 0; k < 256; ++k) p += shv[g][k] * sw2s[k * 32 + j];
    float gacc = sbg[j], uacc = sbf[j];
#pragma unroll 8
    for (int i = 0; i < 32; ++i) {
        float tv = __shfl(p, i, 32);
        gacc += tv * swgs[i * 32 + j];
        uacc += tv * swfs[i * 32 + j];
    }
    float sig = 1.f / (1.f + expf(-gacc));
    float sv = acc[(size_t)token * 288 + 256 + j] + ssb[j] + sig * uacc;
    float s1 = sv, s2 = sv * sv;
    for (int off = 16; off; off >>= 1) {
        s1 += __shfl_xor(s1, off, 32);
        s2 += __shfl_xor(s2, off, 32);
    }
    float mean = s1 * (1.f / 32.f);
    float var = s2 * (1.f / 32.f) - mean * mean;
    float v = (sv - mean) * rsqrtf(var + 1e-5f) * sgam[j] + sbet[j];
    float mx = v;
    for (int off = 16; off; off >>= 1) mx = fmaxf(mx, __shfl_xor(mx, off, 32));
    float e = expf(v - mx);
    float ssum = e;
    for (int off = 16; off; off >>= 1) ssum += __shfl_xor(ssum, off, 32);
    wbuf[(size_t)(tok_base + token) * 32 + j] = e / ssum;
}

// ---------------------------------------------------------------------------
// PASS 2: grid (BT/32). Block = 32 tokens x all 32 features (f-lockstep).
// Recompute y_f, accumulate w_f*y_f in regs, direct store to out.
// ---------------------------------------------------------------------------
__global__ __launch_bounds__(512, 4) void pass2_kernel(
    const float* __restrict__ x, const float* __restrict__ w1, const float* __restrict__ b1,
    const float* __restrict__ b2, const float* __restrict__ bg, const float* __restrict__ bfv_,
    const float* __restrict__ gamma, const float* __restrict__ beta,
    const float* __restrict__ wsk, const float* __restrict__ bsk,
    const _Float16* __restrict__ w2t, const _Float16* __restrict__ wgt,
    const _Float16* __restrict__ wft, const float* __restrict__ wbuf,
    float* __restrict__ out)
{
    __shared__ __align__(16) char smem[59264];
    _Float16* As = (_Float16*)smem;             // 32x264 fp16
    _Float16* Bs = (_Float16*)(smem + 16896);   // GRN B tiles
    float* xs  = (float*)(smem + 53760);        // 32
    float* red = (float*)(smem + 53888);        // 256
    float* mv  = (float*)(smem + 54912);        // 64
    float* wls = (float*)(smem + 55168);        // 32x32 f32 [m][f]

    const int t = threadIdx.x;
    const int w = t >> 6;
    const int mgrp = w >> 2, ngrp = w & 3;
    const int ln = t & 15, q = (t & 63) >> 4;
    const size_t tokg = (size_t)blockIdx.x * 32;

#pragma unroll
    for (int i = 0; i < 2; ++i) {
        int idx = t + i * 512;
        wls[idx] = wbuf[tokg * 32 + idx];       // [m][f] contiguous
    }

    float4v oacc[4];
#pragma unroll
    for (int nt = 0; nt < 4; ++nt)
#pragma unroll
        for (int r = 0; r < 4; ++r) oacc[nt][r] = 0.f;

    float4v yv[4];
    for (int f = 0; f < F; ++f) {
        grn32(f, tokg, x, w1, b1, b2, bg, bfv_, gamma, beta, wsk, bsk,
              w2t, wgt, wft, As, Bs, xs, red, mv, t, mgrp, ngrp, ln, q, yv);
#pragma unroll
        for (int r = 0; r < 4; ++r) {
            int m = mgrp * 16 + q * 4 + r;
            float wfv = wls[m * 32 + f];
#pragma unroll
            for (int nt = 0; nt < 4; ++nt)
                oacc[nt][r] += wfv * yv[nt][r];
        }
    }
#pragma unroll
    for (int nt = 0; nt < 4; ++nt) {
        int n = ngrp * 64 + nt * 16 + ln;
#pragma unroll
        for (int r = 0; r < 4; ++r) {
            int m = mgrp * 16 + q * 4 + r;
            out[(tokg + m) * H + n] = oacc[nt][r];
        }
    }
}

// ---------------------------------------------------------------------------
extern "C" void kernel_launch(void* const* d_in, const int* in_sizes, int n_in,
                              void* d_out, int out_size, void* d_ws, size_t ws_size,
                              hipStream_t stream)
{
    (void)in_sizes; (void)n_in; (void)out_size; (void)ws_size;
    const float* x    = (const float*)d_in[0];
    const float* w1   = (const float*)d_in[1];
    const float* b1   = (const float*)d_in[2];
    const float* w2   = (const float*)d_in[3];
    const float* b2   = (const float*)d_in[4];
    const float* wg   = (const float*)d_in[5];
    const float* bg   = (const float*)d_in[6];
    const float* wf   = (const float*)d_in[7];
    const float* bfp  = (const float*)d_in[8];
    const float* gamma= (const float*)d_in[9];
    const float* beta = (const float*)d_in[10];
    const float* wsk  = (const float*)d_in[11];
    const float* bsk  = (const float*)d_in[12];
    const float* sw1  = (const float*)d_in[13];
    const float* sb1  = (const float*)d_in[14];
    const float* sw2  = (const float*)d_in[15];
    const float* sb2  = (const float*)d_in[16];
    const float* swg  = (const float*)d_in[17];
    const float* sbg  = (const float*)d_in[18];
    const float* swf  = (const float*)d_in[19];
    const float* sbf  = (const float*)d_in[20];
    const float* sgam = (const float*)d_in[21];
    const float* sbet = (const float*)d_in[22];
    const float* ssw  = (const float*)d_in[23];
    const float* ssb  = (const float*)d_in[24];

    char* ws = (char*)d_ws;
    _Float16* wt   = (_Float16*)ws;                     // 12.58 MB
    _Float16* wcat = (_Float16*)(ws + 12582912);        // 4.72 MB
    float* acc     = (float*)(ws + 17301504);           // CHUNK x 288 f32 = 4.72 MB
    float* wbuf    = (float*)(ws + 22020096);           // BT x 32 f32 = 2 MB
    float* out     = (float*)d_out;
    // total ws: 24.1 MB (known safe: ws_size >= 26.3 MB)

    hipLaunchKernelGGL(transpose_w_kernel, dim3(1536), dim3(256), 0, stream, w2, wg, wf, wt);
    hipLaunchKernelGGL(transpose_s_kernel, dim3(640), dim3(256), 0, stream, sw1, ssw, wcat);
    for (int c = 0; c < BT / CHUNK; ++c) {
        int tb = c * CHUNK;
        hipMemsetAsync(acc, 0, (size_t)CHUNK * 288 * sizeof(float), stream);
        hipLaunchKernelGGL(pass1_kernel, dim3(CHUNK / 32, 4), dim3(512), 0, stream,
                           x, w1, b1, b2, bg, bfp, gamma, beta, wsk, bsk,
                           wt, wt + 2097152, wt + 2 * 2097152, wcat, acc, tb);
        hipLaunchKernelGGL(tail_kernel, dim3(CHUNK / 8), dim3(256), 0, stream,
                           acc, sb1, ssb, sw2, sb2, swg, sbg, swf, sbf,
                           sgam, sbet, wbuf, tb);
    }
    hipLaunchKernelGGL(pass2_kernel, dim3(BT / 32), dim3(512), 0, stream,
                       x, w1, b1, b2, bg, bfp, gamma, beta, wsk, bsk,
                       wt, wt + 2097152, wt + 2 * 2097152, wbuf, out);
}